// Round 10
// baseline (352.483 us; speedup 1.0000x reference)
//
#include <hip/hip_runtime.h>
#include <hip/hip_bf16.h>

typedef __attribute__((ext_vector_type(8))) short short8;
typedef __attribute__((ext_vector_type(4))) float f32x4;

#define LL 16
#define NP3 23
#define NE 10
#define NC 128
#define RB 512           // rows per block
#define THREADS 512
#define BHALF 98304      // one K-half of B: 96 frags * 64 lanes * 16 B
#define XSTR 24          // xs row stride in bf16 (48 B: 16B-aligned, rows+4 -> bank+16)
#define WSTR 29          // wys row stride in bf16

static __device__ __forceinline__ short f2bs(float f) {
    __hip_bfloat16 h = __float2bfloat16(f);
    short s;
    __builtin_memcpy(&s, &h, 2);
    return s;
}
static __device__ __forceinline__ float b2f(short s) {
    unsigned u = ((unsigned)(unsigned short)s) << 16;
    float f;
    __builtin_memcpy(&f, &u, 4);
    return f;
}

// ---- kernel 1: pack U3/U2 -> fragment-major bf16 B, kk-major K, K-half-major ----
// K = kk*16 + i  (kk = Wy3 slot 0..22, slot 23 = U2; i = x-feature 0..15)
// frag g = kh*96 + nt*6 + ks; lane: n = nt*16+(lane&15); K = kh*192+ks*32+(lane>>4)*8+j
__global__ void build_B(const float* __restrict__ U3, const float* __restrict__ U2,
                        __hip_bfloat16* __restrict__ Bf) {
    int g = blockIdx.x;              // 0..191
    int kh = g / 96, r96 = g % 96;
    int nt = r96 / 6, ks = r96 % 6;
    int lane = threadIdx.x;
    int n    = nt * 16 + (lane & 15);
    short8 v;
#pragma unroll
    for (int j = 0; j < 8; ++j) {
        int K  = kh * 192 + ks * 32 + (lane >> 4) * 8 + j;
        int kk = K >> 4, i = K & 15;
        float f;
        if (kk < NP3)    f = U3[((size_t)n * LL + i) * NP3 + kk];
        else if (i < 4)  f = U2[n * 4 + i];
        else             f = 0.f;
        v[j] = f2bs(f);
    }
    *reinterpret_cast<short8*>(Bf + ((size_t)g * 64 + lane) * 8) = v;
}

// DPP partial-sum on the VALU pipe
#define DPP_ADD(v, CTRL)                                                      \
    {                                                                         \
        int _s = __builtin_bit_cast(int, (v));                                \
        int _p = __builtin_amdgcn_update_dpp(0, _s, (CTRL), 0xF, 0xF, true);  \
        (v) += __builtin_bit_cast(float, _p);                                 \
    }

// ---- kernel 2: B-half LDS-resident; wave = 64 rows x full N; branch-free A-build ----
__global__ __launch_bounds__(THREADS, 1)
void contract_k(const float* __restrict__ x, const float* __restrict__ y,
                const float* __restrict__ W3, const float* __restrict__ W2,
                const float* __restrict__ W1, const float* __restrict__ U1,
                const __hip_bfloat16* __restrict__ Bf, float* __restrict__ out) {
    __shared__ __align__(16) char Bs[BHALF];     // 96 KB
    __shared__ __align__(16) short xs[RB][XSTR]; // 24576 B, bf16 x rows
    __shared__ short wys[RB][WSTR];              // 29696 B: 0..22 Wy3, 23..26 Wy2, 27 Wy1, 28 du

    const int tid    = threadIdx.x;
    const int rowblk = blockIdx.x >> 1;
    const int kh     = blockIdx.x & 1;
    const int m0     = rowblk * RB;

    // issue one-time B-half load (lands under staging + Wy phase)
    f32x4 st[12];
    {
        const f32x4* p = reinterpret_cast<const f32x4*>(Bf) + (size_t)kh * (BHALF / 16) + tid;
#pragma unroll
        for (int j = 0; j < 12; ++j) st[j] = p[j * THREADS];
    }

    // stage x rows as bf16: thread = row (64 B coalesced read per thread)
    {
        const f32x4* xp = reinterpret_cast<const f32x4*>(x + (size_t)(m0 + tid) * LL);
        f32x4 v0 = xp[0], v1 = xp[1], v2 = xp[2], v3 = xp[3];
        short8 lo, hi8;
#pragma unroll
        for (int j = 0; j < 4; ++j) {
            lo[j] = f2bs(v0[j]);  lo[j + 4]  = f2bs(v1[j]);
            hi8[j] = f2bs(v2[j]); hi8[j + 4] = f2bs(v3[j]);
        }
        *reinterpret_cast<short8*>(&xs[tid][0]) = lo;
        *reinterpret_cast<short8*>(&xs[tid][8]) = hi8;
    }
    __syncthreads();                 // xs visible (du term below reads it)

    // Wy phase: thread = row; coalesced W loads over c
    {
        const int r = tid;
        const int bb = rowblk * 4 + (r >> 7);
        const int c  = r & (NC - 1);
        float yv[NE];
#pragma unroll
        for (int e = 0; e < NE; ++e) yv[e] = y[(size_t)bb * NE + e];
#pragma unroll
        for (int idx = 0; idx < 29; ++idx) {
            float s = 0.f;
            if (idx < NP3) {
#pragma unroll
                for (int e = 0; e < NE; ++e) s += yv[e] * W3[(e * NP3 + idx) * NC + c];
            } else if (idx < 27) {
#pragma unroll
                for (int e = 0; e < NE; ++e) s += yv[e] * W2[(e * 4 + (idx - NP3)) * NC + c];
            } else if (idx == 27) {
#pragma unroll
                for (int e = 0; e < NE; ++e) s += yv[e] * W1[e * NC + c];
            } else {
#pragma unroll
                for (int w = 0; w < LL; ++w) s += U1[w] * b2f(xs[r][w]);
            }
            wys[r][idx] = f2bs(s);
        }
    }

    // commit B-half to LDS
    {
        f32x4* q = reinterpret_cast<f32x4*>(Bs) + tid;
#pragma unroll
        for (int j = 0; j < 12; ++j) q[j * THREADS] = st[j];
    }
    __syncthreads();     // Bs + wys visible; LDS read-only from here

    const int lane = tid & 63;
    const int wv   = tid >> 6;       // wave owns rows [wv*64, wv*64+64)
    const int lx   = lane & 15;
    const int hi   = lane >> 4;      // 0..3

    // branch-free A-build: A2[rt][ks], lane covers row = wv*64+rt*16+lx,
    // K = kh*192 + ks*32 + hi*8 + j  ->  i = (hi&1)*8+j (addr), kk = kh*12+ks*2+(hi>>1)
    short8 A2[4][6];
#pragma unroll
    for (int rt = 0; rt < 4; ++rt) {
        const int arow = wv * 64 + rt * 16 + lx;
        short8 xv = *reinterpret_cast<const short8*>(&xs[arow][(hi & 1) * 8]);
#pragma unroll
        for (int ks = 0; ks < 6; ++ks) {
            const int kk = kh * 12 + ks * 2 + (hi >> 1);
            short8 av;
            if (kk == NP3) {         // only kh=1, ks=5, hi>=2: U2 slot / zero pad
#pragma unroll
                for (int j = 0; j < 8; ++j)
                    av[j] = ((hi & 1) == 0 && j < 4) ? wys[arow][NP3 + j] : (short)0;
            } else {
                float wk = b2f(wys[arow][kk]);
#pragma unroll
                for (int j = 0; j < 8; ++j) av[j] = f2bs(b2f(xv[j]) * wk);
            }
            A2[rt][ks] = av;
        }
    }

    // xx[rt*4+q] = x[row][lx]  (row = wv*64 + rt*16 + hi*4 + q)
    float xx[16];
#pragma unroll
    for (int u = 0; u < 16; ++u) {
        int row = wv * 64 + (u >> 2) * 16 + hi * 4 + (u & 3);
        xx[u] = b2f(xs[row][lx]);
    }

    float acc_out[16];
#pragma unroll
    for (int u = 0; u < 16; ++u) acc_out[u] = 0.f;

    // main loop: 16 N-tiles (nt == w), 6 k-steps; each b-frag feeds 4 rowtiles
    const short8* BsV = reinterpret_cast<const short8*>(Bs);
#pragma unroll
    for (int nt = 0; nt < 16; ++nt) {
        f32x4 acc[4];
#pragma unroll
        for (int rt = 0; rt < 4; ++rt) acc[rt] = f32x4{0.f, 0.f, 0.f, 0.f};
        __builtin_amdgcn_s_setprio(1);
#pragma unroll
        for (int ks = 0; ks < 6; ++ks) {
            short8 bfrag = BsV[(nt * 6 + ks) * 64 + lane];
#pragma unroll
            for (int rt = 0; rt < 4; ++rt)
                acc[rt] = __builtin_amdgcn_mfma_f32_16x16x32_bf16(A2[rt][ks], bfrag, acc[rt], 0, 0, 0);
        }
        __builtin_amdgcn_s_setprio(0);
        // fold: acc_out += acc * x[row][w=nt]   (broadcast read, 4 addrs/wave)
#pragma unroll
        for (int rt = 0; rt < 4; ++rt)
#pragma unroll
            for (int q = 0; q < 4; ++q) {
                int row = wv * 64 + rt * 16 + hi * 4 + q;
                acc_out[rt * 4 + q] += acc[rt][q] * b2f(xs[row][nt]);
            }
    }

    // epilogue: *x_x (per-lane), sum 16 lanes via DPP mirrors, atomicAdd across kh
#pragma unroll
    for (int u = 0; u < 16; ++u) {
        float v = acc_out[u] * xx[u];
        DPP_ADD(v, 0xB1);    // quad_perm xor1
        DPP_ADD(v, 0x4E);    // quad_perm xor2
        DPP_ADD(v, 0x141);   // row_half_mirror (8)
        DPP_ADD(v, 0x140);   // row_mirror (16)
        if (lx == 0) {
            int row = wv * 64 + (u >> 2) * 16 + hi * 4 + (u & 3);
            float add = v;
            if (kh == 0)
                add += b2f(wys[row][27]) * b2f(wys[row][28]);
            atomicAdd(out + m0 + row, add);
        }
    }
}

extern "C" void kernel_launch(void* const* d_in, const int* in_sizes, int n_in,
                              void* d_out, int out_size, void* d_ws, size_t ws_size,
                              hipStream_t stream) {
    const float* x  = (const float*)d_in[0];
    const float* y  = (const float*)d_in[1];
    const float* U3 = (const float*)d_in[2];
    const float* U2 = (const float*)d_in[3];
    const float* U1 = (const float*)d_in[4];
    const float* W3 = (const float*)d_in[5];
    const float* W2 = (const float*)d_in[6];
    const float* W1 = (const float*)d_in[7];
    __hip_bfloat16* Bf = (__hip_bfloat16*)d_ws;   // 192 frags * 64 lanes * 8 bf16 * 2B

    hipMemsetAsync(d_out, 0, (size_t)out_size * sizeof(float), stream);
    build_B<<<192, 64, 0, stream>>>(U3, U2, Bf);
    contract_k<<<1024, THREADS, 0, stream>>>(x, y, W3, W2, W1, U1, Bf, (float*)d_out);
}

// Round 11
// 152.888 us; speedup vs baseline: 2.3055x; 2.3055x over previous
//
#include <hip/hip_runtime.h>
#include <hip/hip_bf16.h>

typedef __attribute__((ext_vector_type(8))) short short8;
typedef __attribute__((ext_vector_type(4))) float f32x4;

#define LL 16
#define NP3 23
#define NE 10
#define NC 128
#define RB 512           // rows per block
#define THREADS 512
#define BHALF 98304      // one K-half of B: 96 frags * 64 lanes * 16 B
#define XSTR 24          // xs row stride in bf16 (48 B)
#define WSTR 29          // wys row stride in bf16

static __device__ __forceinline__ short f2bs(float f) {
    __hip_bfloat16 h = __float2bfloat16(f);
    short s;
    __builtin_memcpy(&s, &h, 2);
    return s;
}
static __device__ __forceinline__ float b2f(short s) {
    unsigned u = ((unsigned)(unsigned short)s) << 16;
    float f;
    __builtin_memcpy(&f, &u, 4);
    return f;
}

// ---- kernel 1: pack U3/U2 -> fragment-major bf16 B, kk-major K, K-half-major ----
// K = kk*16 + i ; frag g = kh*96 + nt*6 + ks ; lane: n = nt*16+(lane&15),
// K = kh*192 + ks*32 + (lane>>4)*8 + j       (verified R10)
__global__ void build_B(const float* __restrict__ U3, const float* __restrict__ U2,
                        __hip_bfloat16* __restrict__ Bf) {
    int g = blockIdx.x;              // 0..191
    int kh = g / 96, r96 = g % 96;
    int nt = r96 / 6, ks = r96 % 6;
    int lane = threadIdx.x;
    int n    = nt * 16 + (lane & 15);
    short8 v;
#pragma unroll
    for (int j = 0; j < 8; ++j) {
        int K  = kh * 192 + ks * 32 + (lane >> 4) * 8 + j;
        int kk = K >> 4, i = K & 15;
        float f;
        if (kk < NP3)    f = U3[((size_t)n * LL + i) * NP3 + kk];
        else if (i < 4)  f = U2[n * 4 + i];
        else             f = 0.f;
        v[j] = f2bs(f);
    }
    *reinterpret_cast<short8*>(Bf + ((size_t)g * 64 + lane) * 8) = v;
}

// DPP partial-sum on the VALU pipe
#define DPP_ADD(v, CTRL)                                                      \
    {                                                                         \
        int _s = __builtin_bit_cast(int, (v));                                \
        int _p = __builtin_amdgcn_update_dpp(0, _s, (CTRL), 0xF, 0xF, true);  \
        (v) += __builtin_bit_cast(float, _p);                                 \
    }

// ---- kernel 2: B-half LDS-resident; wave = 64 rows (2 sweeps x 32) x full N ----
__global__ __launch_bounds__(THREADS, 2)
void contract_k(const float* __restrict__ x, const float* __restrict__ y,
                const float* __restrict__ W3, const float* __restrict__ W2,
                const float* __restrict__ W1, const float* __restrict__ U1,
                const __hip_bfloat16* __restrict__ Bf, float* __restrict__ out) {
    __shared__ __align__(16) char Bs[BHALF];     // 96 KB
    __shared__ __align__(16) short xs[RB][XSTR]; // 24576 B, bf16 x rows
    __shared__ short wys[RB][WSTR];              // 29696 B: 0..22 Wy3, 23..26 Wy2, 27 Wy1, 28 du

    const int tid    = threadIdx.x;
    const int rowblk = blockIdx.x >> 1;
    const int kh     = blockIdx.x & 1;
    const int m0     = rowblk * RB;

    // issue one-time B-half load (lands under staging + Wy phase)
    {
        f32x4 st[12];
        {
            const f32x4* p = reinterpret_cast<const f32x4*>(Bf) + (size_t)kh * (BHALF / 16) + tid;
#pragma unroll
            for (int j = 0; j < 12; ++j) st[j] = p[j * THREADS];
        }

        // stage x rows as bf16: thread = row (64 B coalesced read per thread)
        {
            const f32x4* xp = reinterpret_cast<const f32x4*>(x + (size_t)(m0 + tid) * LL);
            f32x4 v0 = xp[0], v1 = xp[1], v2 = xp[2], v3 = xp[3];
            short8 lo, hi8;
#pragma unroll
            for (int j = 0; j < 4; ++j) {
                lo[j] = f2bs(v0[j]);  lo[j + 4]  = f2bs(v1[j]);
                hi8[j] = f2bs(v2[j]); hi8[j + 4] = f2bs(v3[j]);
            }
            *reinterpret_cast<short8*>(&xs[tid][0]) = lo;
            *reinterpret_cast<short8*>(&xs[tid][8]) = hi8;
        }
        __syncthreads();             // xs visible (du term below reads it)

        // Wy phase: thread = row; coalesced W loads over c
        {
            const int r = tid;
            const int bb = rowblk * 4 + (r >> 7);
            const int c  = r & (NC - 1);
            float yv[NE];
#pragma unroll
            for (int e = 0; e < NE; ++e) yv[e] = y[(size_t)bb * NE + e];
#pragma unroll
            for (int idx = 0; idx < 29; ++idx) {
                float s = 0.f;
                if (idx < NP3) {
#pragma unroll
                    for (int e = 0; e < NE; ++e) s += yv[e] * W3[(e * NP3 + idx) * NC + c];
                } else if (idx < 27) {
#pragma unroll
                    for (int e = 0; e < NE; ++e) s += yv[e] * W2[(e * 4 + (idx - NP3)) * NC + c];
                } else if (idx == 27) {
#pragma unroll
                    for (int e = 0; e < NE; ++e) s += yv[e] * W1[e * NC + c];
                } else {
#pragma unroll
                    for (int w = 0; w < LL; ++w) s += U1[w] * b2f(xs[r][w]);
                }
                wys[r][idx] = f2bs(s);
            }
        }

        // commit B-half to LDS (st dies here -> registers freed for main loop)
        {
            f32x4* q = reinterpret_cast<f32x4*>(Bs) + tid;
#pragma unroll
            for (int j = 0; j < 12; ++j) q[j * THREADS] = st[j];
        }
    }
    __syncthreads();     // Bs + wys visible; LDS read-only from here

    const int lane = tid & 63;
    const int wv   = tid >> 6;       // wave owns rows [wv*64, wv*64+64)
    const int lx   = lane & 15;
    const int hi   = lane >> 4;      // 0..3

    const short8* BsV = reinterpret_cast<const short8*>(Bs);

    // two sweeps of 32 rows: A2[2][6] = 48 VGPR (fits the 128-VGPR cap, no spill)
#pragma unroll
    for (int s2 = 0; s2 < 2; ++s2) {
        const int rb = wv * 64 + s2 * 32;

        // branch-free A-build: lane covers row = rb + rt*16 + lx,
        // K = kh*192 + ks*32 + hi*8 + j -> i = (hi&1)*8+j, kk = kh*12 + ks*2 + (hi>>1)
        short8 A2[2][6];
#pragma unroll
        for (int rt = 0; rt < 2; ++rt) {
            const int arow = rb + rt * 16 + lx;
            short8 xv = *reinterpret_cast<const short8*>(&xs[arow][(hi & 1) * 8]);
#pragma unroll
            for (int ks = 0; ks < 6; ++ks) {
                const int kk = kh * 12 + ks * 2 + (hi >> 1);
                short8 av;
                if (kk == NP3) {     // only kh=1, ks=5, hi>=2: U2 slot / zero pad
#pragma unroll
                    for (int j = 0; j < 8; ++j)
                        av[j] = ((hi & 1) == 0 && j < 4) ? wys[arow][NP3 + j] : (short)0;
                } else {
                    float wk = b2f(wys[arow][kk]);
#pragma unroll
                    for (int j = 0; j < 8; ++j) av[j] = f2bs(b2f(xv[j]) * wk);
                }
                A2[rt][ks] = av;
            }
        }

        // xx[rt*4+q] = x[row][lx]   (row = rb + rt*16 + hi*4 + q)
        float xx[8];
#pragma unroll
        for (int u = 0; u < 8; ++u) {
            int row = rb + (u >> 2) * 16 + hi * 4 + (u & 3);
            xx[u] = b2f(xs[row][lx]);
        }

        float acc_out[8];
#pragma unroll
        for (int u = 0; u < 8; ++u) acc_out[u] = 0.f;

        // main loop: 16 N-tiles (nt == w), 6 k-steps; each b-frag feeds 2 rowtiles
#pragma unroll
        for (int nt = 0; nt < 16; ++nt) {
            f32x4 acc[2];
            acc[0] = f32x4{0.f, 0.f, 0.f, 0.f};
            acc[1] = f32x4{0.f, 0.f, 0.f, 0.f};
            __builtin_amdgcn_s_setprio(1);
#pragma unroll
            for (int ks = 0; ks < 6; ++ks) {
                short8 bfrag = BsV[(nt * 6 + ks) * 64 + lane];
                acc[0] = __builtin_amdgcn_mfma_f32_16x16x32_bf16(A2[0][ks], bfrag, acc[0], 0, 0, 0);
                acc[1] = __builtin_amdgcn_mfma_f32_16x16x32_bf16(A2[1][ks], bfrag, acc[1], 0, 0, 0);
            }
            __builtin_amdgcn_s_setprio(0);
            // fold: acc_out += acc * x[row][w=nt]  (4-way broadcast ds_read_b32)
#pragma unroll
            for (int rt = 0; rt < 2; ++rt)
#pragma unroll
                for (int q = 0; q < 4; ++q) {
                    int row = rb + rt * 16 + hi * 4 + q;
                    acc_out[rt * 4 + q] += acc[rt][q] * b2f(xs[row][nt]);
                }
        }

        // epilogue: *x_x (per-lane col), 16-lane DPP reduce, atomicAdd across kh
#pragma unroll
        for (int u = 0; u < 8; ++u) {
            float v = acc_out[u] * xx[u];
            DPP_ADD(v, 0xB1);    // quad_perm xor1
            DPP_ADD(v, 0x4E);    // quad_perm xor2
            DPP_ADD(v, 0x141);   // row_half_mirror (8)
            DPP_ADD(v, 0x140);   // row_mirror (16)
            if (lx == 0) {
                int row = rb + (u >> 2) * 16 + hi * 4 + (u & 3);
                float add = v;
                if (kh == 0)
                    add += b2f(wys[row][27]) * b2f(wys[row][28]);
                atomicAdd(out + m0 + row, add);
            }
        }
    }
}

extern "C" void kernel_launch(void* const* d_in, const int* in_sizes, int n_in,
                              void* d_out, int out_size, void* d_ws, size_t ws_size,
                              hipStream_t stream) {
    const float* x  = (const float*)d_in[0];
    const float* y  = (const float*)d_in[1];
    const float* U3 = (const float*)d_in[2];
    const float* U2 = (const float*)d_in[3];
    const float* U1 = (const float*)d_in[4];
    const float* W3 = (const float*)d_in[5];
    const float* W2 = (const float*)d_in[6];
    const float* W1 = (const float*)d_in[7];
    __hip_bfloat16* Bf = (__hip_bfloat16*)d_ws;   // 192 frags * 64 lanes * 8 bf16 * 2B

    hipMemsetAsync(d_out, 0, (size_t)out_size * sizeof(float), stream);
    build_B<<<192, 64, 0, stream>>>(U3, U2, Bf);
    contract_k<<<1024, THREADS, 0, stream>>>(x, y, W3, W2, W1, U1, Bf, (float*)d_out);
}